// Round 10
// baseline (863.530 us; speedup 1.0000x reference)
//
#include <hip/hip_runtime.h>
#include <hip/hip_bf16.h>

#define NNODE 8192
#define DIM 512
#define NEDGE 131072
#define NLAYER 4
#define PADIDX 127

typedef float4 f4;
typedef __attribute__((ext_vector_type(8))) short s16x8;
typedef __attribute__((ext_vector_type(4))) float f32x4;

static __device__ __forceinline__ float bf2f(unsigned short h){
  return __uint_as_float(((unsigned int)h) << 16);
}
static __device__ __forceinline__ unsigned short f2bf(float f){
  unsigned int u = __float_as_uint(f);
  u += 0x7FFFu + ((u >> 16) & 1u);
  return (unsigned short)(u >> 16);
}
static __device__ __forceinline__ float blo(unsigned int u){ return __uint_as_float(u << 16); }
static __device__ __forceinline__ float bhi(unsigned int u){ return __uint_as_float(u & 0xFFFF0000u); }
static __device__ __forceinline__ unsigned int pack2(float a, float b){
  return (unsigned int)f2bf(a) | ((unsigned int)f2bf(b) << 16);
}

// ---- dtype detect: even halfwords of a bf16 array are plausible bf16 values ----
__global__ void k_detect(const unsigned short* __restrict__ src, int* __restrict__ flag){
  int lane = threadIdx.x;
  float v = bf2f(src[2*lane]);
  float a = fabsf(v);
  bool good = (a > 1e-6f) && (a < 0.5f);
  unsigned long long m = __ballot(good);
  if (lane == 0) *flag = (__popcll(m) >= 32) ? 1 : 0;
}

__global__ void k_convert(const void* __restrict__ src, float* __restrict__ dst, int n,
                          const int* __restrict__ flag){
  int f = *flag;
  int i = blockIdx.x*blockDim.x + threadIdx.x;
  int stride = gridDim.x*blockDim.x;
  if (f){
    const unsigned short* s = (const unsigned short*)src;
    for (; i<n; i+=stride) dst[i] = bf2f(s[i]);
  } else {
    const float* s = (const float*)src;
    for (; i<n; i+=stride) dst[i] = s[i];
  }
}

// ---- LDS-tiled transpose-convert: src [L][512][C] f32/bf16 -> dst [L][C][512] bf16 ----
// 64x64 tiles; reads and writes both coalesced.
__global__ void k_convT(const void* __restrict__ src, unsigned short* __restrict__ dst,
                        int C, int dstOff, int dstStride, const int* __restrict__ flag){
  __shared__ unsigned short t[64][65];
  int f = *flag;
  int c0 = blockIdx.x*64, r0 = blockIdx.y*64;
  size_t mat = (size_t)blockIdx.z*512*C;
  int tx = threadIdx.x & 63, ty = threadIdx.x >> 6;   // 256 threads: 64 x 4
  #pragma unroll
  for (int i=0;i<16;i++){
    int r = ty + i*4;
    size_t si = mat + (size_t)(r0+r)*C + c0 + tx;     // coalesced in tx
    unsigned short o = f ? ((const unsigned short*)src)[si] : f2bf(((const float*)src)[si]);
    t[tx][r] = o;                                     // transposed into LDS
  }
  __syncthreads();
  size_t dbase = (size_t)blockIdx.z*dstStride;
  #pragma unroll
  for (int i=0;i<16;i++){
    int c = ty + i*4;
    dst[dbase + (size_t)(dstOff + c0 + c)*512 + r0 + tx] = t[c][tx];  // coalesced in tx
  }
}

// combined qkv bias [L][2048] f32
__global__ void k_bias(const void* __restrict__ bq, const void* __restrict__ bkv,
                       float* __restrict__ dst, const int* __restrict__ flag){
  int f = *flag;
  int gid = blockIdx.x*blockDim.x + threadIdx.x;
  if (gid >= NLAYER*2048) return;
  int l = gid >> 11, j = gid & 2047;
  float val;
  if (j < 512)
    val = f ? bf2f(((const unsigned short*)bq)[l*512+j]) : ((const float*)bq)[l*512+j];
  else
    val = f ? bf2f(((const unsigned short*)bkv)[l*1536 + j-512]) : ((const float*)bkv)[l*1536 + j-512];
  dst[gid] = val;
}

// ---- CSR build (stores source col directly) ----
__global__ void k_zero_i(int* __restrict__ p, int n){
  int i = blockIdx.x*blockDim.x + threadIdx.x;
  if (i<n) p[i]=0;
}

__global__ void k_count(const int* __restrict__ row, int* __restrict__ counts){
  int e = blockIdx.x*blockDim.x + threadIdx.x;
  if (e<NEDGE) atomicAdd(&counts[row[e]], 1);
}

__global__ __launch_bounds__(1024) void k_scan(const int* __restrict__ counts,
                                               int* __restrict__ offs, int* __restrict__ cursor){
  __shared__ int part[1024];
  int tid = threadIdx.x;
  int local[8]; int s = 0;
  #pragma unroll
  for (int j=0;j<8;j++){ local[j]=s; s += counts[tid*8+j]; }
  part[tid]=s;
  __syncthreads();
  for (int off=1; off<1024; off<<=1){
    int t = (tid>=off) ? part[tid-off] : 0;
    __syncthreads();
    part[tid] += t;
    __syncthreads();
  }
  int base = (tid>0) ? part[tid-1] : 0;
  #pragma unroll
  for (int j=0;j<8;j++){ int o = base + local[j]; offs[tid*8+j]=o; cursor[tid*8+j]=o; }
  if (tid==1023) offs[8192] = part[1023];
}

__global__ void k_fill(const int* __restrict__ ei, int* __restrict__ cursor, int* __restrict__ ecol){
  int e = blockIdx.x*blockDim.x + threadIdx.x;
  if (e<NEDGE){ int p = atomicAdd(&cursor[ei[e]], 1); ecol[p] = ei[NEDGE+e]; }
}

// ---- init: x = embed[tok], v = coord @ vec_proj + b ; bf16 mirror of x ----
__global__ void k_init(const int* __restrict__ tok, const void* __restrict__ emb,
                       const void* __restrict__ coord, const void* __restrict__ vw,
                       const void* __restrict__ vb, const int* __restrict__ flag,
                       float* __restrict__ x, float* __restrict__ v,
                       unsigned short* __restrict__ xbf){
  int f = *flag;
  int i = blockIdx.x*blockDim.x + threadIdx.x;
  if (i >= NNODE*DIM) return;
  int n = i >> 9, d = i & 511;
  int t = tok[n];
  float xv, c0, c1, c2, w0, w1, w2, bb;
  if (f){
    const unsigned short* e = (const unsigned short*)emb;
    const unsigned short* c = (const unsigned short*)coord;
    const unsigned short* wv = (const unsigned short*)vw;
    const unsigned short* bv = (const unsigned short*)vb;
    xv = bf2f(e[(t<<9)|d]);
    c0 = bf2f(c[n*3+0]); c1 = bf2f(c[n*3+1]); c2 = bf2f(c[n*3+2]);
    w0 = bf2f(wv[d]); w1 = bf2f(wv[512+d]); w2 = bf2f(wv[1024+d]);
    bb = bf2f(bv[d]);
  } else {
    const float* e = (const float*)emb;
    const float* c = (const float*)coord;
    const float* wv = (const float*)vw;
    const float* bv = (const float*)vb;
    xv = e[(t<<9)|d];
    c0 = c[n*3+0]; c1 = c[n*3+1]; c2 = c[n*3+2];
    w0 = wv[d]; w1 = wv[512+d]; w2 = wv[1024+d];
    bb = bv[d];
  }
  x[i] = xv;
  xbf[i] = f2bf(xv);
  v[i] = c0*w0 + c1*w1 + c2*w2 + bb;
}

// ---- bf16 MFMA GEMM, direct-global (no LDS, no barriers) ----
// K=512 short-pipe regime: A rows and B^T rows are L2-resident; fragment loads go
// straight to VGPRs, scoreboard pipelines across K-iters with zero sync stalls.
// 128x128 tile, 4 waves (2x2), each wave 64x64 via 4x4 frags of 16x16x32.
// Per instruction, lanes {i,i+16,i+32,i+48} fetch 64 contiguous bytes.
// mode 0: f32 store; 1: f32 +=; 2: bf16 store
#define BM 128
#define BN 128

__global__ __launch_bounds__(256) void k_mgemm(const unsigned short* __restrict__ A,
                                               const unsigned short* __restrict__ Bt,
                                               const float* __restrict__ bias,
                                               void* __restrict__ C,
                                               int ldc, int mode){
  int tid  = threadIdx.x;
  int lane = tid & 63;
  int w    = tid >> 6;
  int wr   = (w >> 1) * 64;
  int wc   = (w & 1) * 64;
  int bm   = blockIdx.y * BM;
  int bn   = blockIdx.x * BN;

  int arow = bm + wr + (lane & 15);   // + m*16
  int brow = bn + wc + (lane & 15);   // + n*16
  int ksl  = lane >> 4;               // 0..3

  f32x4 acc[4][4];
  #pragma unroll
  for (int m=0;m<4;m++)
    #pragma unroll
    for (int n=0;n<4;n++) acc[m][n] = (f32x4){0.f,0.f,0.f,0.f};

  #pragma unroll 2
  for (int kt = 0; kt < 512; kt += 64){
    s16x8 af[4][2], bfr[4][2];
    #pragma unroll
    for (int m=0;m<4;m++)
      #pragma unroll
      for (int kk=0;kk<2;kk++)
        af[m][kk] = *(const s16x8*)(A + (size_t)(arow + m*16)*512 + kt + (kk*4 + ksl)*8);
    #pragma unroll
    for (int n=0;n<4;n++)
      #pragma unroll
      for (int kk=0;kk<2;kk++)
        bfr[n][kk] = *(const s16x8*)(Bt + (size_t)(brow + n*16)*512 + kt + (kk*4 + ksl)*8);
    #pragma unroll
    for (int kk=0;kk<2;kk++)
      #pragma unroll
      for (int m=0;m<4;m++)
        #pragma unroll
        for (int n=0;n<4;n++)
          acc[m][n] = __builtin_amdgcn_mfma_f32_16x16x32_bf16(af[m][kk], bfr[n][kk], acc[m][n], 0, 0, 0);
  }

  // C/D layout: col = lane&15, row = (lane>>4)*4 + j
  int colb = bn + wc + (lane & 15);
  int rowb = bm + wr + ((lane >> 4) << 2);
  float bb[4];
  #pragma unroll
  for (int n=0;n<4;n++) bb[n] = bias[colb + n*16];
  #pragma unroll
  for (int m=0;m<4;m++){
    #pragma unroll
    for (int n=0;n<4;n++){
      #pragma unroll
      for (int j=0;j<4;j++){
        size_t o = (size_t)(rowb + m*16 + j)*ldc + (colb + n*16);
        float val = acc[m][n][j] + bb[n];
        if (mode == 2)      ((unsigned short*)C)[o] = f2bf(val);
        else if (mode == 1) ((float*)C)[o] += val;
        else                ((float*)C)[o] = val;
      }
    }
  }
}

// ---- in-place gating: qkv[n, 1536+d] = bf16( v_v * v[n,d] ) ----
__global__ void k_vvip(unsigned short* __restrict__ qkv, const float* __restrict__ v){
  int gid = blockIdx.x*blockDim.x + threadIdx.x;   // NNODE*64
  int n = gid >> 6, d8 = (gid & 63) * 8;
  unsigned short* p = qkv + (size_t)n*2048 + 1536 + d8;
  uint4 u = *(uint4*)p;
  f4 v0 = *(const f4*)(v + (size_t)n*512 + d8);
  f4 v1 = *(const f4*)(v + (size_t)n*512 + d8 + 4);
  uint4 o;
  o.x = pack2(blo(u.x)*v0.x, bhi(u.x)*v0.y);
  o.y = pack2(blo(u.y)*v0.z, bhi(u.y)*v0.w);
  o.z = pack2(blo(u.z)*v1.x, bhi(u.z)*v1.y);
  o.w = pack2(blo(u.w)*v1.z, bhi(u.w)*v1.w);
  *(uint4*)p = o;
}

// ---- fused edge-score + aggregation, MLP-batched ----
// qkv row layout per node: [0:512) q | [512:1024) k | [1024:1536) v_s | [1536:2048) vv
__global__ __launch_bounds__(256) void k_fused(const int* __restrict__ offs,
                                               const int* __restrict__ ecol,
                                               const unsigned short* __restrict__ qkv,
                                               float* __restrict__ x,
                                               unsigned short* __restrict__ xbf,
                                               unsigned short* __restrict__ aggvbf){
  __shared__ unsigned short qs[512];
  __shared__ float ews[64];
  __shared__ int cols[64];
  int n = blockIdx.x, tid = threadIdx.x;
  int beg = offs[n], end = offs[n+1];
  if (tid < 64)
    *(uint4*)&qs[tid*8] = *(const uint4*)(qkv + (size_t)n*2048 + tid*8);
  float a0=0.f, a1=0.f, a2=0.f, a3=0.f;
  int half = tid >> 7;
  int d4 = (tid & 127) * 4;
  size_t srcoff = half ? 1536 : 1024;   // vv : v_s
  int lane = tid & 63, w = tid >> 6;

  for (int cb = beg; cb < end; cb += 64){
    int cnt = min(64, end - cb);
    __syncthreads();
    // phase 1: one wave per edge; batch 4 edges per wave for load-level parallelism
    uint4 qu = *(const uint4*)(qs + lane*8);
    for (int t0 = 0; t0 < 16 && w + 4*t0 < cnt; t0 += 4){
      int cc[4]; uint4 ku[4];
      #pragma unroll
      for (int s=0;s<4;s++){ int j = w + 4*(t0+s); cc[s] = (j < cnt) ? ecol[cb+j] : 0; }
      #pragma unroll
      for (int s=0;s<4;s++){ int j = w + 4*(t0+s);
        if (j < cnt) ku[s] = *(const uint4*)(qkv + (size_t)cc[s]*2048 + 512 + lane*8); }
      #pragma unroll
      for (int s=0;s<4;s++){
        int j = w + 4*(t0+s);
        if (j < cnt){
          float sd = blo(qu.x)*blo(ku[s].x) + bhi(qu.x)*bhi(ku[s].x)
                   + blo(qu.y)*blo(ku[s].y) + bhi(qu.y)*bhi(ku[s].y)
                   + blo(qu.z)*blo(ku[s].z) + bhi(qu.z)*bhi(ku[s].z)
                   + blo(qu.w)*blo(ku[s].w) + bhi(qu.w)*bhi(ku[s].w);
          #pragma unroll
          for (int o=32;o;o>>=1) sd += __shfl_xor(sd, o, 64);
          if (lane == 0){ ews[j] = sd; cols[j] = cc[s]; }
        }
      }
    }
    __syncthreads();
    // phase 2: batch 8 payload loads before accumulating (8 loads in flight)
    int j = 0;
    for (; j + 8 <= cnt; j += 8){
      float wg[8]; uint2 u[8];
      #pragma unroll
      for (int t=0;t<8;t++){ wg[t] = ews[j+t];
        u[t] = *(const uint2*)(qkv + (size_t)cols[j+t]*2048 + srcoff + d4); }
      #pragma unroll
      for (int t=0;t<8;t++){
        a0 += wg[t]*blo(u[t].x); a1 += wg[t]*bhi(u[t].x);
        a2 += wg[t]*blo(u[t].y); a3 += wg[t]*bhi(u[t].y);
      }
    }
    for (; j < cnt; j++){
      float wgt = ews[j];
      uint2 u = *(const uint2*)(qkv + (size_t)cols[j]*2048 + srcoff + d4);
      a0 += wgt*blo(u.x); a1 += wgt*bhi(u.x);
      a2 += wgt*blo(u.y); a3 += wgt*bhi(u.y);
    }
  }

  size_t base = (size_t)n*512 + d4;
  if (half == 0){
    f4 xv = *(const f4*)(x + base);
    xv.x += a0; xv.y += a1; xv.z += a2; xv.w += a3;
    *(f4*)(x + base) = xv;
    uint2 o; o.x = pack2(xv.x, xv.y); o.y = pack2(xv.z, xv.w);
    *(uint2*)(xbf + base) = o;
  } else {
    uint2 o; o.x = pack2(a0, a1); o.y = pack2(a2, a3);
    *(uint2*)(aggvbf + base) = o;
  }
}

__global__ void k_out(const int* __restrict__ tok, const float* __restrict__ x,
                      float* __restrict__ out, int out_size){
  int i = blockIdx.x*blockDim.x + threadIdx.x;
  if (i>=out_size) return;
  if (i < NNODE*DIM){
    int n = i>>9;
    out[i] = (tok[n]==PADIDX) ? 0.f : x[i];
  } else {
    int m = i - NNODE*DIM;
    out[i] = (m < NNODE && tok[m]==PADIDX) ? 1.f : 0.f;
  }
}

extern "C" void kernel_launch(void* const* d_in, const int* in_sizes, int n_in,
                              void* d_out, int out_size, void* d_ws, size_t ws_size,
                              hipStream_t stream){
  (void)in_sizes; (void)n_in; (void)ws_size;
  const int*  tok   = (const int*)d_in[0];
  const void* coord = d_in[1];
  // d_in[2] src_distance, d_in[3] src_edge_type: unused by reference
  const int*  ei    = (const int*)d_in[4];
  const void* emb   = d_in[5];
  const void* vpw   = d_in[6];
  const void* vpb   = d_in[7];
  const void* Wq    = d_in[8];
  const void* bq    = d_in[9];
  const void* Wkv   = d_in[10];
  const void* bkv   = d_in[11];
  const void* Wvm   = d_in[12];
  const void* bvm   = d_in[13];

  char* p = (char*)d_ws;
  auto alloc = [&](size_t nbytes)->char*{ char* r = p; p += (nbytes + 255) & ~(size_t)255; return r; };
  float* x      = (float*)alloc((size_t)NNODE*DIM*4);
  float* v      = (float*)alloc((size_t)NNODE*DIM*4);
  unsigned short* qkv    = (unsigned short*)alloc((size_t)NNODE*2048*2);
  unsigned short* xbf    = (unsigned short*)alloc((size_t)NNODE*DIM*2);
  unsigned short* aggvbf = (unsigned short*)alloc((size_t)NNODE*DIM*2);
  unsigned short* WqkvT  = (unsigned short*)alloc((size_t)NLAYER*2048*DIM*2);
  unsigned short* WvmT   = (unsigned short*)alloc((size_t)NLAYER*DIM*DIM*2);
  float* cbqkv  = (float*)alloc((size_t)NLAYER*2048*4);
  float* cbvm   = (float*)alloc((size_t)NLAYER*DIM*4);
  int* counts   = (int*)alloc(8192*4);
  int* offs     = (int*)alloc(8193*4);
  int* cursor   = (int*)alloc(8192*4);
  int* ecol     = (int*)alloc((size_t)NEDGE*4);
  int* flag     = (int*)alloc(4);

  k_detect<<<1,64,0,stream>>>((const unsigned short*)Wq, flag);
  k_convert<<<8,256,0,stream>>>(bvm, cbvm, NLAYER*DIM, flag);
  k_bias<<<(NLAYER*2048+255)/256,256,0,stream>>>(bq, bkv, cbqkv, flag);
  // weights -> bf16 B^T (tiled transpose): Wq rows 0..511, Wkv rows 512..2047
  k_convT<<<dim3(8, 8, NLAYER),256,0,stream>>>(Wq,  WqkvT, 512,  0,   2048*512, flag);
  k_convT<<<dim3(24,8, NLAYER),256,0,stream>>>(Wkv, WqkvT, 1536, 512, 2048*512, flag);
  k_convT<<<dim3(8, 8, NLAYER),256,0,stream>>>(Wvm, WvmT,  512,  0,   512*512,  flag);

  // CSR by destination, storing source col directly
  k_zero_i<<<32,256,0,stream>>>(counts, 8192);
  k_count<<<NEDGE/256,256,0,stream>>>(ei, counts);
  k_scan<<<1,1024,0,stream>>>(counts, offs, cursor);
  k_fill<<<NEDGE/256,256,0,stream>>>(ei, cursor, ecol);

  k_init<<<(NNODE*DIM)/256,256,0,stream>>>(tok, emb, coord, vpw, vpb, flag, x, v, xbf);

  for (int l=0;l<NLAYER;l++){
    const unsigned short* WqkvT_l = WqkvT + (size_t)l*2048*DIM;
    const unsigned short* WvmT_l  = WvmT  + (size_t)l*DIM*DIM;
    const float* bqkv_l = cbqkv + (size_t)l*2048;
    const float* bvm_l  = cbvm  + (size_t)l*DIM;
    k_mgemm<<<dim3(2048/BN, NNODE/BM),256,0,stream>>>(xbf, WqkvT_l, bqkv_l, qkv, 2048, 2);
    k_vvip<<<NNODE*64/256,256,0,stream>>>(qkv, v);
    k_fused<<<NNODE,256,0,stream>>>(offs, ecol, qkv, x, xbf, aggvbf);
    k_mgemm<<<dim3(DIM/BN, NNODE/BM),256,0,stream>>>(aggvbf, WvmT_l, bvm_l, v, 512, 1);
  }

  int ob = (out_size+255)/256;
  k_out<<<ob,256,0,stream>>>(tok, x, (float*)d_out, out_size);
}

// Round 11
// 673.961 us; speedup vs baseline: 1.2813x; 1.2813x over previous
//
#include <hip/hip_runtime.h>
#include <hip/hip_bf16.h>

#define NNODE 8192
#define DIM 512
#define NEDGE 131072
#define NLAYER 4
#define PADIDX 127

typedef float4 f4;
typedef __attribute__((ext_vector_type(8))) short s16x8;
typedef __attribute__((ext_vector_type(4))) float f32x4;

static __device__ __forceinline__ float bf2f(unsigned short h){
  return __uint_as_float(((unsigned int)h) << 16);
}
static __device__ __forceinline__ unsigned short f2bf(float f){
  unsigned int u = __float_as_uint(f);
  u += 0x7FFFu + ((u >> 16) & 1u);
  return (unsigned short)(u >> 16);
}
static __device__ __forceinline__ float blo(unsigned int u){ return __uint_as_float(u << 16); }
static __device__ __forceinline__ float bhi(unsigned int u){ return __uint_as_float(u & 0xFFFF0000u); }
static __device__ __forceinline__ unsigned int pack2(float a, float b){
  return (unsigned int)f2bf(a) | ((unsigned int)f2bf(b) << 16);
}

// ---- dtype detect: even halfwords of a bf16 array are plausible bf16 values ----
__global__ void k_detect(const unsigned short* __restrict__ src, int* __restrict__ flag){
  int lane = threadIdx.x;
  float v = bf2f(src[2*lane]);
  float a = fabsf(v);
  bool good = (a > 1e-6f) && (a < 0.5f);
  unsigned long long m = __ballot(good);
  if (lane == 0) *flag = (__popcll(m) >= 32) ? 1 : 0;
}

__global__ void k_convert(const void* __restrict__ src, float* __restrict__ dst, int n,
                          const int* __restrict__ flag){
  int f = *flag;
  int i = blockIdx.x*blockDim.x + threadIdx.x;
  int stride = gridDim.x*blockDim.x;
  if (f){
    const unsigned short* s = (const unsigned short*)src;
    for (; i<n; i+=stride) dst[i] = bf2f(s[i]);
  } else {
    const float* s = (const float*)src;
    for (; i<n; i+=stride) dst[i] = s[i];
  }
}

// ---- LDS-tiled transpose-convert: src [L][512][C] f32/bf16 -> dst [L][C][512] bf16 ----
__global__ void k_convT(const void* __restrict__ src, unsigned short* __restrict__ dst,
                        int C, int dstOff, int dstStride, const int* __restrict__ flag){
  __shared__ unsigned short t[64][65];
  int f = *flag;
  int c0 = blockIdx.x*64, r0 = blockIdx.y*64;
  size_t mat = (size_t)blockIdx.z*512*C;
  int tx = threadIdx.x & 63, ty = threadIdx.x >> 6;   // 256 threads: 64 x 4
  #pragma unroll
  for (int i=0;i<16;i++){
    int r = ty + i*4;
    size_t si = mat + (size_t)(r0+r)*C + c0 + tx;     // coalesced in tx
    unsigned short o = f ? ((const unsigned short*)src)[si] : f2bf(((const float*)src)[si]);
    t[tx][r] = o;                                     // transposed into LDS
  }
  __syncthreads();
  size_t dbase = (size_t)blockIdx.z*dstStride;
  #pragma unroll
  for (int i=0;i<16;i++){
    int c = ty + i*4;
    dst[dbase + (size_t)(dstOff + c0 + c)*512 + r0 + tx] = t[c][tx];  // coalesced in tx
  }
}

// combined qkv bias [L][2048] f32
__global__ void k_bias(const void* __restrict__ bq, const void* __restrict__ bkv,
                       float* __restrict__ dst, const int* __restrict__ flag){
  int f = *flag;
  int gid = blockIdx.x*blockDim.x + threadIdx.x;
  if (gid >= NLAYER*2048) return;
  int l = gid >> 11, j = gid & 2047;
  float val;
  if (j < 512)
    val = f ? bf2f(((const unsigned short*)bq)[l*512+j]) : ((const float*)bq)[l*512+j];
  else
    val = f ? bf2f(((const unsigned short*)bkv)[l*1536 + j-512]) : ((const float*)bkv)[l*1536 + j-512];
  dst[gid] = val;
}

// ---- CSR build (stores source col directly) ----
__global__ void k_zero_i(int* __restrict__ p, int n){
  int i = blockIdx.x*blockDim.x + threadIdx.x;
  if (i<n) p[i]=0;
}

__global__ void k_count(const int* __restrict__ row, int* __restrict__ counts){
  int e = blockIdx.x*blockDim.x + threadIdx.x;
  if (e<NEDGE) atomicAdd(&counts[row[e]], 1);
}

__global__ __launch_bounds__(1024) void k_scan(const int* __restrict__ counts,
                                               int* __restrict__ offs, int* __restrict__ cursor){
  __shared__ int part[1024];
  int tid = threadIdx.x;
  int local[8]; int s = 0;
  #pragma unroll
  for (int j=0;j<8;j++){ local[j]=s; s += counts[tid*8+j]; }
  part[tid]=s;
  __syncthreads();
  for (int off=1; off<1024; off<<=1){
    int t = (tid>=off) ? part[tid-off] : 0;
    __syncthreads();
    part[tid] += t;
    __syncthreads();
  }
  int base = (tid>0) ? part[tid-1] : 0;
  #pragma unroll
  for (int j=0;j<8;j++){ int o = base + local[j]; offs[tid*8+j]=o; cursor[tid*8+j]=o; }
  if (tid==1023) offs[8192] = part[1023];
}

__global__ void k_fill(const int* __restrict__ ei, int* __restrict__ cursor, int* __restrict__ ecol){
  int e = blockIdx.x*blockDim.x + threadIdx.x;
  if (e<NEDGE){ int p = atomicAdd(&cursor[ei[e]], 1); ecol[p] = ei[NEDGE+e]; }
}

// ---- init: x = embed[tok], v = coord @ vec_proj + b ; bf16 mirror of x ----
__global__ void k_init(const int* __restrict__ tok, const void* __restrict__ emb,
                       const void* __restrict__ coord, const void* __restrict__ vw,
                       const void* __restrict__ vb, const int* __restrict__ flag,
                       float* __restrict__ x, float* __restrict__ v,
                       unsigned short* __restrict__ xbf){
  int f = *flag;
  int i = blockIdx.x*blockDim.x + threadIdx.x;
  if (i >= NNODE*DIM) return;
  int n = i >> 9, d = i & 511;
  int t = tok[n];
  float xv, c0, c1, c2, w0, w1, w2, bb;
  if (f){
    const unsigned short* e = (const unsigned short*)emb;
    const unsigned short* c = (const unsigned short*)coord;
    const unsigned short* wv = (const unsigned short*)vw;
    const unsigned short* bv = (const unsigned short*)vb;
    xv = bf2f(e[(t<<9)|d]);
    c0 = bf2f(c[n*3+0]); c1 = bf2f(c[n*3+1]); c2 = bf2f(c[n*3+2]);
    w0 = bf2f(wv[d]); w1 = bf2f(wv[512+d]); w2 = bf2f(wv[1024+d]);
    bb = bf2f(bv[d]);
  } else {
    const float* e = (const float*)emb;
    const float* c = (const float*)coord;
    const float* wv = (const float*)vw;
    const float* bv = (const float*)vb;
    xv = e[(t<<9)|d];
    c0 = c[n*3+0]; c1 = c[n*3+1]; c2 = c[n*3+2];
    w0 = wv[d]; w1 = wv[512+d]; w2 = wv[1024+d];
    bb = bv[d];
  }
  x[i] = xv;
  xbf[i] = f2bf(xv);
  v[i] = c0*w0 + c1*w1 + c2*w2 + bb;
}

// ---- bf16 MFMA GEMM (R4-proven single-buffer m97 structure) ----
// 128x128 tile, BK=64, 4 waves (2x2), 4x4 frags of 16x16x32.
// mode 0: f32 store; 1: f32 +=; 2: bf16 store
#define BM 128
#define BN 128
#define BK 64

static __device__ __forceinline__ void gload16(const void* g, void* l){
  __builtin_amdgcn_global_load_lds(
      (const __attribute__((address_space(1))) void*)g,
      (__attribute__((address_space(3))) void*)l, 16, 0, 0);
}

__global__ __launch_bounds__(256) void k_mgemm(const unsigned short* __restrict__ A,
                                               const unsigned short* __restrict__ Bt,
                                               const float* __restrict__ bias,
                                               void* __restrict__ C,
                                               int ldc, int mode){
  __shared__ alignas(16) unsigned short As[BM*BK];
  __shared__ alignas(16) unsigned short Bs[BN*BK];
  int tid  = threadIdx.x;
  int lane = tid & 63;
  int w    = tid >> 6;
  int wr   = (w >> 1) * 64;
  int wc   = (w & 1) * 64;
  int bm   = blockIdx.y * BM;
  int bn   = blockIdx.x * BN;

  f32x4 acc[4][4];
  #pragma unroll
  for (int m=0;m<4;m++)
    #pragma unroll
    for (int n=0;n<4;n++) acc[m][n] = (f32x4){0.f,0.f,0.f,0.f};

  int srow = tid >> 3;
  int sp   = tid & 7;
  char* AsB = (char*)As;
  char* BsB = (char*)Bs;

  for (int kt = 0; kt < 512; kt += BK){
    if (kt) __syncthreads();
    #pragma unroll
    for (int i=0;i<4;i++){
      int row  = i*32 + srow;
      int slot = sp ^ (row & 7);
      gload16((const char*)A + (((size_t)(bm + row)) << 10) + (size_t)((kt + slot*8) << 1),
              AsB + i*4096 + w*1024);
    }
    #pragma unroll
    for (int i=0;i<4;i++){
      int row  = i*32 + srow;
      int slot = sp ^ (row & 7);
      gload16((const char*)Bt + (((size_t)(bn + row)) << 10) + (size_t)((kt + slot*8) << 1),
              BsB + i*4096 + w*1024);
    }
    __syncthreads();

    s16x8 af[4][2], bfr[4][2];
    #pragma unroll
    for (int m=0;m<4;m++){
      int row = wr + m*16 + (lane & 15);
      #pragma unroll
      for (int kk=0;kk<2;kk++){
        int slot = kk*4 + (lane >> 4);
        af[m][kk] = *(const s16x8*)(AsB + row*128 + ((slot ^ (row & 7)) << 4));
      }
    }
    #pragma unroll
    for (int n=0;n<4;n++){
      int row = wc + n*16 + (lane & 15);
      #pragma unroll
      for (int kk=0;kk<2;kk++){
        int slot = kk*4 + (lane >> 4);
        bfr[n][kk] = *(const s16x8*)(BsB + row*128 + ((slot ^ (row & 7)) << 4));
      }
    }
    #pragma unroll
    for (int kk=0;kk<2;kk++)
      #pragma unroll
      for (int m=0;m<4;m++)
        #pragma unroll
        for (int n=0;n<4;n++)
          acc[m][n] = __builtin_amdgcn_mfma_f32_16x16x32_bf16(af[m][kk], bfr[n][kk], acc[m][n], 0, 0, 0);
  }

  // C/D layout: col = lane&15, row = (lane>>4)*4 + j
  int colb = bn + wc + (lane & 15);
  int rowb = bm + wr + ((lane >> 4) << 2);
  float bb[4];
  #pragma unroll
  for (int n=0;n<4;n++) bb[n] = bias[colb + n*16];
  #pragma unroll
  for (int m=0;m<4;m++){
    #pragma unroll
    for (int n=0;n<4;n++){
      #pragma unroll
      for (int j=0;j<4;j++){
        size_t o = (size_t)(rowb + m*16 + j)*ldc + (colb + n*16);
        float val = acc[m][n][j] + bb[n];
        if (mode == 2)      ((unsigned short*)C)[o] = f2bf(val);
        else if (mode == 1) ((float*)C)[o] += val;
        else                ((float*)C)[o] = val;
      }
    }
  }
}

// ---- in-place gating: qkv[n, 1536+d] = bf16( v_v * v[n,d] ) ----
__global__ void k_vvip(unsigned short* __restrict__ qkv, const float* __restrict__ v){
  int gid = blockIdx.x*blockDim.x + threadIdx.x;   // NNODE*64
  int n = gid >> 6, d8 = (gid & 63) * 8;
  unsigned short* p = qkv + (size_t)n*2048 + 1536 + d8;
  uint4 u = *(uint4*)p;
  f4 v0 = *(const f4*)(v + (size_t)n*512 + d8);
  f4 v1 = *(const f4*)(v + (size_t)n*512 + d8 + 4);
  uint4 o;
  o.x = pack2(blo(u.x)*v0.x, bhi(u.x)*v0.y);
  o.y = pack2(blo(u.y)*v0.z, bhi(u.y)*v0.w);
  o.z = pack2(blo(u.z)*v1.x, bhi(u.z)*v1.y);
  o.w = pack2(blo(u.w)*v1.z, bhi(u.w)*v1.w);
  *(uint4*)p = o;
}

// ---- fused edge-score + aggregation, wave-autonomous (no barriers in loop) ----
// qkv row layout per node: [0:512) q | [512:1024) k | [1024:1536) v_s | [1536:2048) vv
// Each wave owns whole edges: load k row -> dot(q,k) -> shuffle reduce -> load
// v_s+vv rows -> accumulate ew*payload into per-lane registers (lane owns dims
// lane*8..lane*8+8). Cross-wave partials combined once via LDS at the end.
__global__ __launch_bounds__(256) void k_fused(const int* __restrict__ offs,
                                               const int* __restrict__ ecol,
                                               const unsigned short* __restrict__ qkv,
                                               float* __restrict__ x,
                                               unsigned short* __restrict__ xbf,
                                               unsigned short* __restrict__ aggvbf){
  __shared__ float redS[4][512];
  __shared__ float redV[4][512];
  int n = blockIdx.x, tid = threadIdx.x;
  int lane = tid & 63, w = tid >> 6;
  int beg = offs[n], end = offs[n+1];

  uint4 qu = *(const uint4*)(qkv + (size_t)n*2048 + lane*8);
  float as[8], av[8];
  #pragma unroll
  for (int k=0;k<8;k++){ as[k]=0.f; av[k]=0.f; }

  auto edge = [&](int c, uint4 ku, uint4 vs, uint4 vv){
    float sd = blo(qu.x)*blo(ku.x) + bhi(qu.x)*bhi(ku.x)
             + blo(qu.y)*blo(ku.y) + bhi(qu.y)*bhi(ku.y)
             + blo(qu.z)*blo(ku.z) + bhi(qu.z)*bhi(ku.z)
             + blo(qu.w)*blo(ku.w) + bhi(qu.w)*bhi(ku.w);
    #pragma unroll
    for (int o=32;o;o>>=1) sd += __shfl_xor(sd, o, 64);
    as[0] += sd*blo(vs.x); as[1] += sd*bhi(vs.x);
    as[2] += sd*blo(vs.y); as[3] += sd*bhi(vs.y);
    as[4] += sd*blo(vs.z); as[5] += sd*bhi(vs.z);
    as[6] += sd*blo(vs.w); as[7] += sd*bhi(vs.w);
    av[0] += sd*blo(vv.x); av[1] += sd*bhi(vv.x);
    av[2] += sd*blo(vv.y); av[3] += sd*bhi(vv.y);
    av[4] += sd*blo(vv.z); av[5] += sd*bhi(vv.z);
    av[6] += sd*blo(vv.w); av[7] += sd*bhi(vv.w);
  };

  int j = beg + w;
  // 2 edges per pass: 6 x 16B loads in flight before any dependent math
  for (; j + 4 < end; j += 8){
    int c0 = ecol[j], c1 = ecol[j+4];
    const unsigned short* b0 = qkv + (size_t)c0*2048;
    const unsigned short* b1 = qkv + (size_t)c1*2048;
    uint4 ku0 = *(const uint4*)(b0 + 512  + lane*8);
    uint4 ku1 = *(const uint4*)(b1 + 512  + lane*8);
    uint4 vs0 = *(const uint4*)(b0 + 1024 + lane*8);
    uint4 vv0 = *(const uint4*)(b0 + 1536 + lane*8);
    uint4 vs1 = *(const uint4*)(b1 + 1024 + lane*8);
    uint4 vv1 = *(const uint4*)(b1 + 1536 + lane*8);
    edge(c0, ku0, vs0, vv0);
    edge(c1, ku1, vs1, vv1);
  }
  if (j < end){
    int c0 = ecol[j];
    const unsigned short* b0 = qkv + (size_t)c0*2048;
    uint4 ku0 = *(const uint4*)(b0 + 512  + lane*8);
    uint4 vs0 = *(const uint4*)(b0 + 1024 + lane*8);
    uint4 vv0 = *(const uint4*)(b0 + 1536 + lane*8);
    edge(c0, ku0, vs0, vv0);
  }

  // cross-wave reduction
  #pragma unroll
  for (int k=0;k<8;k+=4){
    *(f4*)&redS[w][lane*8+k] = (f4){as[k],as[k+1],as[k+2],as[k+3]};
    *(f4*)&redV[w][lane*8+k] = (f4){av[k],av[k+1],av[k+2],av[k+3]};
  }
  __syncthreads();
  int d0 = tid*2;
  float s0 = redS[0][d0]+redS[1][d0]+redS[2][d0]+redS[3][d0];
  float s1 = redS[0][d0+1]+redS[1][d0+1]+redS[2][d0+1]+redS[3][d0+1];
  float v0 = redV[0][d0]+redV[1][d0]+redV[2][d0]+redV[3][d0];
  float v1 = redV[0][d0+1]+redV[1][d0+1]+redV[2][d0+1]+redV[3][d0+1];
  size_t base = (size_t)n*512 + d0;
  float2 xv = *(const float2*)(x + base);
  xv.x += s0; xv.y += s1;
  *(float2*)(x + base) = xv;
  ((unsigned int*)xbf)[base>>1]    = pack2(xv.x, xv.y);
  ((unsigned int*)aggvbf)[base>>1] = pack2(v0, v1);
}

__global__ void k_out(const int* __restrict__ tok, const float* __restrict__ x,
                      float* __restrict__ out, int out_size){
  int i = blockIdx.x*blockDim.x + threadIdx.x;
  if (i>=out_size) return;
  if (i < NNODE*DIM){
    int n = i>>9;
    out[i] = (tok[n]==PADIDX) ? 0.f : x[i];
  } else {
    int m = i - NNODE*DIM;
    out[i] = (m < NNODE && tok[m]==PADIDX) ? 1.f : 0.f;
  }
}

extern "C" void kernel_launch(void* const* d_in, const int* in_sizes, int n_in,
                              void* d_out, int out_size, void* d_ws, size_t ws_size,
                              hipStream_t stream){
  (void)in_sizes; (void)n_in; (void)ws_size;
  const int*  tok   = (const int*)d_in[0];
  const void* coord = d_in[1];
  // d_in[2] src_distance, d_in[3] src_edge_type: unused by reference
  const int*  ei    = (const int*)d_in[4];
  const void* emb   = d_in[5];
  const void* vpw   = d_in[6];
  const void* vpb   = d_in[7];
  const void* Wq    = d_in[8];
  const void* bq    = d_in[9];
  const void* Wkv   = d_in[10];
  const void* bkv   = d_in[11];
  const void* Wvm   = d_in[12];
  const void* bvm   = d_in[13];

  char* p = (char*)d_ws;
  auto alloc = [&](size_t nbytes)->char*{ char* r = p; p += (nbytes + 255) & ~(size_t)255; return r; };
  float* x      = (float*)alloc((size_t)NNODE*DIM*4);
  float* v      = (float*)alloc((size_t)NNODE*DIM*4);
  unsigned short* qkv    = (unsigned short*)alloc((size_t)NNODE*2048*2);
  unsigned short* xbf    = (unsigned short*)alloc((size_t)NNODE*DIM*2);
  unsigned short* aggvbf = (unsigned short*)alloc((size_t)NNODE*DIM*2);
  unsigned short* WqkvT  = (unsigned short*)alloc((size_t)NLAYER*2048*DIM*2);
  unsigned short* WvmT   = (unsigned short*)alloc((size_t)NLAYER*DIM*DIM*2);
  float* cbqkv  = (float*)alloc((size_t)NLAYER*2048*4);
  float* cbvm   = (float*)alloc((size_t)NLAYER*DIM*4);
  int* counts   = (int*)alloc(8192*4);
  int* offs     = (int*)alloc(8193*4);
  int* cursor   = (int*)alloc(8192*4);
  int* ecol     = (int*)alloc((size_t)NEDGE*4);
  int* flag     = (int*)alloc(4);

  k_detect<<<1,64,0,stream>>>((const unsigned short*)Wq, flag);
  k_convert<<<8,256,0,stream>>>(bvm, cbvm, NLAYER*DIM, flag);
  k_bias<<<(NLAYER*2048+255)/256,256,0,stream>>>(bq, bkv, cbqkv, flag);
  // weights -> bf16 B^T (tiled transpose): Wq rows 0..511, Wkv rows 512..2047
  k_convT<<<dim3(8, 8, NLAYER),256,0,stream>>>(Wq,  WqkvT, 512,  0,   2048*512, flag);
  k_convT<<<dim3(24,8, NLAYER),256,0,stream>>>(Wkv, WqkvT, 1536, 512, 2048*512, flag);
  k_convT<<<dim3(8, 8, NLAYER),256,0,stream>>>(Wvm, WvmT,  512,  0,   512*512,  flag);

  // CSR by destination, storing source col directly
  k_zero_i<<<32,256,0,stream>>>(counts, 8192);
  k_count<<<NEDGE/256,256,0,stream>>>(ei, counts);
  k_scan<<<1,1024,0,stream>>>(counts, offs, cursor);
  k_fill<<<NEDGE/256,256,0,stream>>>(ei, cursor, ecol);

  k_init<<<(NNODE*DIM)/256,256,0,stream>>>(tok, emb, coord, vpw, vpb, flag, x, v, xbf);

  for (int l=0;l<NLAYER;l++){
    const unsigned short* WqkvT_l = WqkvT + (size_t)l*2048*DIM;
    const unsigned short* WvmT_l  = WvmT  + (size_t)l*DIM*DIM;
    const float* bqkv_l = cbqkv + (size_t)l*2048;
    const float* bvm_l  = cbvm  + (size_t)l*DIM;
    k_mgemm<<<dim3(2048/BN, NNODE/BM),256,0,stream>>>(xbf, WqkvT_l, bqkv_l, qkv, 2048, 2);
    k_vvip<<<NNODE*64/256,256,0,stream>>>(qkv, v);
    k_fused<<<NNODE,256,0,stream>>>(offs, ecol, qkv, x, xbf, aggvbf);
    k_mgemm<<<dim3(DIM/BN, NNODE/BM),256,0,stream>>>(aggvbf, WvmT_l, bvm_l, v, 512, 1);
  }

  int ob = (out_size+255)/256;
  k_out<<<ob,256,0,stream>>>(tok, x, (float*)d_out, out_size);
}